// Round 2
// baseline (233.151 us; speedup 1.0000x reference)
//
#include <hip/hip_runtime.h>
#include <cstdint>

// B=4, S=2048, D_IN=D_OUT=1024; softmax scale = 1/sqrt(1024) = 0.03125
// exp without max-subtraction is safe (|scores| ~< 3); L = rowsum via atomics;
// 1/L folded into PV epilogue.
//
// gemm_qkv2: 256x256 tile, BK=64, 8 waves (2Mx4N), 512 threads, 8-phase
// schedule (HK-style T3+T4+T5). LDS 128 KiB: As[2buf][2half][128][64] +
// Bs[...]. Each K-tile = 4 phases; phase (a,b) computes C-quadrant
// [a*128,+128)x[b*128,+128) over K=64 (16 MFMA/wave). Read localization:
//   A-half0 read only in P1 (a=0 frags reused in P2), B-half0 in P1
//   (kept in regs for P4), B-half1 in P2 (reused P3), A-half1 in P3.
// So each half-region is dead after its read phase -> restage tile t+2's
// half into the SAME buffer mid-tile: P2 stages (t+2){A0,B0}, P3 {B1},
// P4 {A1}.  Counted vmcnt (issue-stream derived, 2 loads/half):
//   steady: P1-end vmcnt(10), P2-end vmcnt(12), P3-end none, P4-end vmcnt(12)
//   tail t14: 10/8/-/4, t15: 2/0/-/-  (exact; drain only at the very end).
// R1 bugfix: buffer stride is 32768 B (2 halves x 16384 B), NOT 65536 —
// the wrong stride made odd-tile A land on Bs[0] and odd-tile B land past
// the LDS allocation -> garbage -> NaN. Strides are named constants now.
// Barriers are raw s_barrier fused with the waits in one asm("memory") block
// so the compiler can't move LDS/global ops across them. setprio(1) wraps
// each MFMA cluster (T5 pays only on phase-split schedules).
// XOR-chunk LDS swizzle identical to the verified 128^2 kernel: LDS row r,
// 16B-position p holds source chunk p ^ (r&7); reads at (quad ^ (l16&7))*16
// XOR 64 bytes for the high k-half. Conflict-free.

typedef __attribute__((ext_vector_type(8))) __bf16 bf16x8;
typedef __attribute__((ext_vector_type(4))) float f32x4;

#define BK 64

__device__ __forceinline__ unsigned short f2bf(float f) {
  union { float f; unsigned u; } v; v.f = f;
  unsigned r = v.u + 0x7fffu + ((v.u >> 16) & 1u);  // RNE
  return (unsigned short)(r >> 16);
}

__device__ __forceinline__ void gload_lds16(const void* g, void* l) {
  __builtin_amdgcn_global_load_lds(
      (const __attribute__((address_space(1))) void*)g,
      (__attribute__((address_space(3))) void*)l, 16, 0, 0);
}

// ------------- fused fp32->bf16 conversion (X + weights) + L zero ----------
__global__ __launch_bounds__(256)
void cvt_all(const float* __restrict__ X, const float* __restrict__ Wq,
             const float* __restrict__ Wk, const float* __restrict__ Wv,
             unsigned short* __restrict__ Xbf, unsigned short* __restrict__ Wall,
             float* __restrict__ L) {
  const int bid = blockIdx.x;
  if (bid >= 11264) {  // 4 blocks zero L[4][2048]
    float4* p = (float4*)(L + (size_t)(bid - 11264) * 2048);
    p[threadIdx.x] = (float4){0.f, 0.f, 0.f, 0.f};
    p[threadIdx.x + 256] = (float4){0.f, 0.f, 0.f, 0.f};
    return;
  }
  const float* src;
  unsigned short* dst;
  int i;
  if (bid < 8192) {
    src = X; dst = Xbf; i = bid * 256 + threadIdx.x;
  } else {
    const int m = bid - 8192;
    const int sel = m >> 10;
    src = (sel == 0) ? Wq : (sel == 1) ? Wk : Wv;
    dst = Wall + (size_t)sel * 1048576;
    i = (m & 1023) * 256 + threadIdx.x;
  }
  float4 v = ((const float4*)src)[i];
  ushort4 o;
  o.x = f2bf(v.x); o.y = f2bf(v.y); o.z = f2bf(v.z); o.w = f2bf(v.w);
  ((ushort4*)dst)[i] = o;
}

// -------------------- fused QKV GEMM: 256x256 8-phase --------------------
// A = Xbf [8192][1024], B = Wall [3072][1024]; grid 384 = 32(M) x 12(N).
// bx tile: 0-3 -> Q, 4-7 -> K, 8-11 -> V transposed into Vt[b][e][s].

#define BUFSTR 32768  // bytes per buf  (= 2 halves)
#define HSTR   16384  // bytes per half (= 128 rows x 128 B)
#define SSTR    8192  // bytes per s-subregion (64 rows)

#define BAR1 do { asm volatile("s_barrier\n\ts_waitcnt lgkmcnt(0)" ::: "memory"); \
                  __builtin_amdgcn_sched_barrier(0); } while (0)
#define BAR2 do { asm volatile("s_barrier" ::: "memory"); } while (0)
#define VBAR(W) do { asm volatile("s_waitcnt vmcnt(" #W ")\n\ts_barrier" ::: "memory"); } while (0)

#define STG_A(buf, H, s, k2) gload_lds16( \
    Abase + (offA + (unsigned)(((H)*128 + (s)*64) * 2048) + (k2)), \
    AsB + ((buf)*BUFSTR + (H)*HSTR + (s)*SSTR) + ldsW)
#define STG_B(buf, H, s, k2) gload_lds16( \
    Bbase + (offB + (unsigned)(((H)*128 + (s)*64) * 2048) + (k2)), \
    BsB + ((buf)*BUFSTR + (H)*HSTR + (s)*SSTR) + ldsW)

#define RD_A(buf, a) do { \
  const char* _ba = AsB + (buf)*BUFSTR + (a)*HSTR; \
  _Pragma("unroll") \
  for (int i = 0; i < 4; ++i) { \
    af[i][0] = *(const bf16x8*)(_ba + (aRd + (unsigned)i*2048u)); \
    af[i][1] = *(const bf16x8*)(_ba + ((aRd + (unsigned)i*2048u) ^ 64u)); \
  } \
} while (0)

#define RD_B(DST, buf, b) do { \
  const char* _bb = BsB + (buf)*BUFSTR + (b)*HSTR; \
  _Pragma("unroll") \
  for (int j = 0; j < 2; ++j) { \
    DST[j][0] = *(const bf16x8*)(_bb + (bRd + (unsigned)j*2048u)); \
    DST[j][1] = *(const bf16x8*)(_bb + ((bRd + (unsigned)j*2048u) ^ 64u)); \
  } \
} while (0)

#define MM(aq, bq, BF) do { \
  __builtin_amdgcn_s_setprio(1); \
  _Pragma("unroll") \
  for (int h = 0; h < 2; ++h) \
    _Pragma("unroll") \
    for (int i = 0; i < 4; ++i) \
      _Pragma("unroll") \
      for (int j = 0; j < 2; ++j) \
        acc[(aq)*4+i][(bq)*2+j] = __builtin_amdgcn_mfma_f32_16x16x32_bf16( \
            af[i][h], BF[j][h], acc[(aq)*4+i][(bq)*2+j], 0, 0, 0); \
  __builtin_amdgcn_s_setprio(0); \
} while (0)

#define PH1_(p, W)     do { RD_A(p, 0); RD_B(b0, p, 0); BAR1; MM(0,0,b0); VBAR(W); } while (0)
#define PH2S(p, k2, W) do { RD_B(b1, p, 1); STG_A(p,0,0,k2); STG_A(p,0,1,k2); \
                            STG_B(p,0,0,k2); STG_B(p,0,1,k2); BAR1; MM(0,1,b1); VBAR(W); } while (0)
#define PH2N(p, W)     do { RD_B(b1, p, 1); BAR1; MM(0,1,b1); VBAR(W); } while (0)
#define PH3S(p, k2)    do { RD_A(p, 1); STG_B(p,1,0,k2); STG_B(p,1,1,k2); \
                            BAR1; MM(1,1,b1); BAR2; } while (0)
#define PH3N(p)        do { RD_A(p, 1); BAR1; MM(1,1,b1); BAR2; } while (0)
#define PH4S(p, k2, W) do { STG_A(p,1,0,k2); STG_A(p,1,1,k2); BAR1; MM(1,0,b0); VBAR(W); } while (0)
#define PH4N(p, W)     do { BAR1; MM(1,0,b0); VBAR(W); } while (0)
#define PH4E(p)        do { BAR1; MM(1,0,b0); } while (0)

__global__ __launch_bounds__(512, 2)
void gemm_qkv2(const unsigned short* __restrict__ A,
               const unsigned short* __restrict__ Bm,
               unsigned short* __restrict__ Qb,
               unsigned short* __restrict__ Kb,
               unsigned short* __restrict__ Vt)
{
  // bijective XCD swizzle (384 % 8 == 0): consecutive tiles share an XCD L2
  const int wg = blockIdx.x;
  const int swz = (wg & 7) * 48 + (wg >> 3);
  const int by = swz / 12, bx = swz % 12;

  __shared__ __align__(16) unsigned short As[2][2][128 * 64];  // 64 KiB
  __shared__ __align__(16) unsigned short Bs[2][2][128 * 64];  // 64 KiB

  const int tid = threadIdx.x;
  const int wave = tid >> 6, lane = tid & 63;
  const int wr = wave >> 2, wc = wave & 3;       // 2x4 wave grid
  const int quad = lane >> 4, l16 = lane & 15;

  const unsigned rsub = (unsigned)(wave * 8 + (lane >> 3));
  const unsigned csb = (unsigned)(((lane & 7) ^ ((lane >> 3) & 7)) * 16);

  const unsigned offA = (unsigned)(by * 256 + rsub) * 2048u + csb;
  const unsigned offB = (unsigned)(bx * 256 + rsub) * 2048u + csb;
  const char* Abase = (const char*)A;
  const char* Bbase = (const char*)Bm;
  char* AsB = (char*)&As[0][0][0];
  char* BsB = (char*)&Bs[0][0][0];
  const unsigned ldsW = (unsigned)(wave * 1024);

  // LDS read bases (within a [half] region of 128 rows x 128 bytes)
  const unsigned aRd = (unsigned)((wr * 64 + l16) * 128) + (unsigned)((quad ^ (l16 & 7)) * 16);
  const unsigned bRd = (unsigned)((wc * 32 + l16) * 128) + (unsigned)((quad ^ (l16 & 7)) * 16);

  f32x4 acc[8][4];
  #pragma unroll
  for (int i = 0; i < 8; ++i)
    #pragma unroll
    for (int j = 0; j < 4; ++j)
      acc[i][j] = (f32x4){0.f, 0.f, 0.f, 0.f};

  bf16x8 af[4][2], b0[2][2], b1[2][2];

  // ---- prologue: stage tiles 0 (buf0) and 1 (buf1), stream order A0,B0,B1,A1
  STG_A(0,0,0,0u);   STG_A(0,0,1,0u);
  STG_B(0,0,0,0u);   STG_B(0,0,1,0u);
  STG_B(0,1,0,0u);   STG_B(0,1,1,0u);
  STG_A(0,1,0,0u);   STG_A(0,1,1,0u);
  STG_A(1,0,0,128u); STG_A(1,0,1,128u);
  STG_B(1,0,0,128u); STG_B(1,0,1,128u);
  STG_B(1,1,0,128u); STG_B(1,1,1,128u);
  STG_A(1,1,0,128u); STG_A(1,1,1,128u);
  VBAR(12);  // tile0 {A0,B0} landed (4 oldest of 16)

  // ---- main loop: tiles 0..13, staging tile t+2 into the just-freed regions
  #pragma unroll 1
  for (int it = 0; it < 7; ++it) {
    const unsigned ka = (unsigned)(2 * it + 2) * 128u;
    const unsigned kb = (unsigned)(2 * it + 3) * 128u;
    PH1_(0, 10); PH2S(0, ka, 12); PH3S(0, ka); PH4S(0, ka, 12);
    PH1_(1, 10); PH2S(1, kb, 12); PH3S(1, kb); PH4S(1, kb, 12);
  }
  // ---- tail: tiles 14, 15 (no staging; exact tightened waits)
  PH1_(0, 10); PH2N(0, 8); PH3N(0); PH4N(0, 4);
  PH1_(1, 2);  PH2N(1, 0); PH3N(1); PH4E(1);

  // ---- epilogue ----
  // rows: by*256 + aq*128 + wr*64 + i*16 + quad*4 + r
  // cols: bx*256 + bq*128 + wc*32 + j*16 + l16
  if (bx < 8) {
    unsigned short* C = (bx < 4) ? Qb : Kb;
    const int cb = (bx < 4) ? (bx * 256 + wc * 32 + l16)
                            : (bx * 256 - 1024 + wc * 32 + l16);
    #pragma unroll
    for (int aq = 0; aq < 2; ++aq)
      #pragma unroll
      for (int i = 0; i < 4; ++i)
        #pragma unroll
        for (int r = 0; r < 4; ++r) {
          const size_t rr = (size_t)(by * 256 + aq * 128 + wr * 64 + i * 16 + quad * 4 + r) * 1024;
          #pragma unroll
          for (int bq = 0; bq < 2; ++bq)
            #pragma unroll
            for (int j = 0; j < 2; ++j)
              C[rr + cb + bq * 128 + j * 16] = f2bf(acc[aq * 4 + i][bq * 2 + j][r]);
        }
  } else {
    const int row0 = by * 256 + wr * 64 + quad * 4;
    const int b = row0 >> 11;  // constant per block (256-row tile within batch)
    unsigned short* Vb = Vt + (size_t)b * 2097152;
    const int e0 = bx * 256 - 2048 + wc * 32 + l16;
    #pragma unroll
    for (int bq = 0; bq < 2; ++bq)
      #pragma unroll
      for (int j = 0; j < 2; ++j) {
        const size_t ee = (size_t)(e0 + bq * 128 + j * 16) * 2048;
        #pragma unroll
        for (int aq = 0; aq < 2; ++aq)
          #pragma unroll
          for (int i = 0; i < 4; ++i) {
            const int s = (row0 + aq * 128 + i * 16) & 2047;
            f32x4 a4 = acc[aq * 4 + i][bq * 2 + j];
            ushort4 o;
            o.x = f2bf(a4[0]); o.y = f2bf(a4[1]);
            o.z = f2bf(a4[2]); o.w = f2bf(a4[3]);
            *(ushort4*)(Vb + ee + s) = o;
          }
      }
  }
}

// -------------------- scores (128x128, BK=64) + exp + rowsum ----------------
// S'[b] = exp(scale*Q@K^T) causal-masked, bf16; L[b][q] += partial rowsums.
// Triangular-packed grid.x (136 tiles), z = batch.
__global__ __launch_bounds__(256, 3)
void gemm_scores(const unsigned short* __restrict__ Q,
                 const unsigned short* __restrict__ Km,
                 unsigned short* __restrict__ S,
                 float* __restrict__ L)
{
  const int t = blockIdx.x;
  const int bz = blockIdx.z;
  int by = (int)((sqrtf(8.f * t + 1.f) - 1.f) * 0.5f);
  while ((by + 1) * (by + 2) / 2 <= t) ++by;
  while (by * (by + 1) / 2 > t) --by;
  const int bx = t - by * (by + 1) / 2;

  __shared__ __align__(16) unsigned short As2[128 * BK];
  __shared__ __align__(16) unsigned short Bs2[128 * BK];

  const int tid = threadIdx.x;
  const int wave = tid >> 6, lane = tid & 63;
  const int wr = wave >> 1, wc = wave & 1;
  const int quad = lane >> 4, l16 = lane & 15;

  const unsigned rsub = wave * 8 + (lane >> 3);
  const unsigned csb = (unsigned)(((lane & 7) ^ ((lane >> 3) & 7)) * 16);

  unsigned offA[4], offB[4];
  #pragma unroll
  for (int s = 0; s < 4; ++s) {
    offA[s] = ((unsigned)(by * 128 + s * 32 + rsub) * 1024u) * 2u + csb;
    offB[s] = ((unsigned)(bx * 128 + s * 32 + rsub) * 1024u) * 2u + csb;
  }
  const char* Abase = (const char*)(Q + (size_t)bz * 2097152);
  const char* Bbase = (const char*)(Km + (size_t)bz * 2097152);

  f32x4 acc[4][4];
  #pragma unroll
  for (int i = 0; i < 4; ++i)
    #pragma unroll
    for (int j = 0; j < 4; ++j)
      acc[i][j] = (f32x4){0.f, 0.f, 0.f, 0.f};

  const int pq = (quad ^ (l16 & 7)) * 8;
  const int aOff = (wr * 64 + l16) * BK + pq;
  const int bOff = (wc * 64 + l16) * BK + pq;

  for (int k0 = 0; k0 < 1024; k0 += BK) {
    const unsigned kb = (unsigned)k0 * 2u;
    #pragma unroll
    for (int s = 0; s < 4; ++s) {
      gload_lds16(Abase + kb + offA[s], As2 + s * 2048 + wave * 512);
      gload_lds16(Bbase + kb + offB[s], Bs2 + s * 2048 + wave * 512);
    }
    __syncthreads();
    #pragma unroll
    for (int h = 0; h < 2; ++h) {
      const int hx = h * 32;
      bf16x8 af[4], bfr[4];
      #pragma unroll
      for (int i = 0; i < 4; ++i)
        af[i] = *(const bf16x8*)(As2 + ((aOff + i * 16 * BK) ^ hx));
      #pragma unroll
      for (int j = 0; j < 4; ++j)
        bfr[j] = *(const bf16x8*)(Bs2 + ((bOff + j * 16 * BK) ^ hx));
      #pragma unroll
      for (int i = 0; i < 4; ++i)
        #pragma unroll
        for (int j = 0; j < 4; ++j)
          acc[i][j] = __builtin_amdgcn_mfma_f32_16x16x32_bf16(af[i], bfr[j], acc[i][j], 0, 0, 0);
    }
    __syncthreads();
  }

  const int row0 = by * 128 + wr * 64 + quad * 4;
  const int col0 = bx * 128 + wc * 64 + l16;
  float* Lb = L + (size_t)bz * 2048;
  unsigned short* C = S + (size_t)bz * 4194304;

  #pragma unroll
  for (int i = 0; i < 4; ++i)
    #pragma unroll
    for (int r = 0; r < 4; ++r) {
      const int grow = row0 + i * 16 + r;
      float ps = 0.f;
      #pragma unroll
      for (int j = 0; j < 4; ++j) {
        const int gcol = col0 + j * 16;
        float e = (gcol <= grow) ? __expf(acc[i][j][r] * 0.03125f) : 0.f;
        acc[i][j][r] = e;
        ps += e;
      }
      #pragma unroll
      for (int m = 8; m > 0; m >>= 1)
        ps += __shfl_xor(ps, m);
      if (l16 == 0) atomicAdd(&Lb[grow], ps);
      const size_t rr = (size_t)grow * 2048;
      #pragma unroll
      for (int j = 0; j < 4; ++j)
        C[rr + col0 + j * 16] = f2bf(acc[i][j][r]);
    }
}

// -------------------- PV (128x128, BK=64) with 1/L normalization ------------
// Out[b] = (P'[b] @ Vt[b]^T) / L; grid (8, 16, 4); kmax = (by+1)*128.
__global__ __launch_bounds__(256, 3)
void gemm_pv(const unsigned short* __restrict__ P,
             const unsigned short* __restrict__ Vt,
             float* __restrict__ Out,
             const float* __restrict__ L)
{
  const int bx = blockIdx.x, by = blockIdx.y, bz = blockIdx.z;

  __shared__ __align__(16) unsigned short As2[128 * BK];
  __shared__ __align__(16) unsigned short Bs2[128 * BK];

  const int tid = threadIdx.x;
  const int wave = tid >> 6, lane = tid & 63;
  const int wr = wave >> 1, wc = wave & 1;
  const int quad = lane >> 4, l16 = lane & 15;

  const unsigned rsub = wave * 8 + (lane >> 3);
  const unsigned csb = (unsigned)(((lane & 7) ^ ((lane >> 3) & 7)) * 16);

  unsigned offA[4], offB[4];
  #pragma unroll
  for (int s = 0; s < 4; ++s) {
    offA[s] = ((unsigned)(by * 128 + s * 32 + rsub) * 2048u) * 2u + csb;
    offB[s] = ((unsigned)(bx * 128 + s * 32 + rsub) * 2048u) * 2u + csb;
  }
  const char* Abase = (const char*)(P + (size_t)bz * 4194304);
  const char* Bbase = (const char*)(Vt + (size_t)bz * 2097152);

  f32x4 acc[4][4];
  #pragma unroll
  for (int i = 0; i < 4; ++i)
    #pragma unroll
    for (int j = 0; j < 4; ++j)
      acc[i][j] = (f32x4){0.f, 0.f, 0.f, 0.f};

  const int kmax = (by + 1) * 128;  // causal truncation, multiple of BK

  const int pq = (quad ^ (l16 & 7)) * 8;
  const int aOff = (wr * 64 + l16) * BK + pq;
  const int bOff = (wc * 64 + l16) * BK + pq;

  for (int k0 = 0; k0 < kmax; k0 += BK) {
    const unsigned kb = (unsigned)k0 * 2u;
    #pragma unroll
    for (int s = 0; s < 4; ++s) {
      gload_lds16(Abase + kb + offA[s], As2 + s * 2048 + wave * 512);
      gload_lds16(Bbase + kb + offB[s], Bs2 + s * 2048 + wave * 512);
    }
    __syncthreads();
    #pragma unroll
    for (int h = 0; h < 2; ++h) {
      const int hx = h * 32;
      bf16x8 af[4], bfr[4];
      #pragma unroll
      for (int i = 0; i < 4; ++i)
        af[i] = *(const bf16x8*)(As2 + ((aOff + i * 16 * BK) ^ hx));
      #pragma unroll
      for (int j = 0; j < 4; ++j)
        bfr[j] = *(const bf16x8*)(Bs2 + ((bOff + j * 16 * BK) ^ hx));
      #pragma unroll
      for (int i = 0; i < 4; ++i)
        #pragma unroll
        for (int j = 0; j < 4; ++j)
          acc[i][j] = __builtin_amdgcn_mfma_f32_16x16x32_bf16(af[i], bfr[j], acc[i][j], 0, 0, 0);
    }
    __syncthreads();
  }

  const int row0 = by * 128 + wr * 64 + quad * 4;
  const int col0 = bx * 128 + wc * 64 + l16;
  float* C = Out + (size_t)bz * 2097152;
  const float* Lb = L + (size_t)bz * 2048;
  #pragma unroll
  for (int i = 0; i < 4; ++i)
    #pragma unroll
    for (int r = 0; r < 4; ++r) {
      const int grow = row0 + i * 16 + r;
      const float inv = 1.0f / Lb[grow];
      const size_t rr = (size_t)grow * 1024;
      #pragma unroll
      for (int j = 0; j < 4; ++j)
        C[rr + col0 + j * 16] = acc[i][j][r] * inv;
    }
}

// -------------------- launch --------------------
extern "C" void kernel_launch(void* const* d_in, const int* in_sizes, int n_in,
                              void* d_out, int out_size, void* d_ws, size_t ws_size,
                              hipStream_t stream) {
  const float* X  = (const float*)d_in[0];
  const float* Wq = (const float*)d_in[1];
  const float* Wk = (const float*)d_in[2];
  const float* Wv = (const float*)d_in[3];
  float* Out = (float*)d_out;

  char* ws = (char*)d_ws;
  unsigned short* Xbf  = (unsigned short*)(ws);              // [8192][1024]    16 MiB
  unsigned short* Wall = (unsigned short*)(ws + 16777216);   // [3072][1024]     6 MiB
  unsigned short* Qbf  = (unsigned short*)(ws + 23068672);   // [8192][1024]    16 MiB
  unsigned short* Kbf  = (unsigned short*)(ws + 39845888);   // [8192][1024]    16 MiB
  unsigned short* Vt   = (unsigned short*)(ws + 56623104);   // [4][1024][2048] 16 MiB
  unsigned short* Sbf  = (unsigned short*)(ws + 73400320);   // [4][2048][2048] 32 MiB
  float*          Lbuf = (float*)(ws + 106954752);           // [4][2048]       32 KiB

  cvt_all<<<11268, 256, 0, stream>>>(X, Wq, Wk, Wv, Xbf, Wall, Lbuf);

  gemm_qkv2<<<384, 512, 0, stream>>>(Xbf, Wall, Qbf, Kbf, Vt);

  gemm_scores<<<dim3(136, 1, 4), 256, 0, stream>>>(Qbf, Kbf, Sbf, Lbuf);

  gemm_pv<<<dim3(8, 16, 4), 256, 0, stream>>>(Sbf, Vt, Out, Lbuf);
}

// Round 4
// 216.991 us; speedup vs baseline: 1.0745x; 1.0745x over previous
//
#include <hip/hip_runtime.h>
#include <cstdint>

// B=4, S=2048, D_IN=D_OUT=1024; softmax scale = 1/sqrt(1024) = 0.03125
// exp without max-subtraction is safe (|scores| ~< 3); L = rowsum via atomics;
// 1/L folded into PV epilogue.
//
// GEMM structure: 128x128 tile, BK=64 (16 KB LDS per matrix), 8-chunk XOR
// swizzle: position p of row r holds source chunk p ^ (r&7); reads are
// ds_read_b128 at (quad ^ (l16&7))*8, ^32 for the high k-half. Conflict-free.
// Staging addresses: uniform base (SGPR) + per-lane 32-bit offset to cut
// VGPR pressure (64-bit pointer arrays cost 32 VGPRs -> 8).
// __launch_bounds__(256,3): cap regs at ~170 so VGPR+acc fits 3 waves/SIMD.
//
// R2 note: a 256x256 8-phase rewrite of gemm_qkv measured 84 us vs this
// structure's 59.6 us (1 block/CU, 2 waves/SIMD lockstep stall + 1.5-round
// grid quantization) -- reverted. This round adds only T1 XCD swizzle:
// qkv: lin%8 -> XCD cluster of 8 consecutive by tile-rows (A-panel 2MB < 4MB L2).
// scores: t' = (t&7)*17 + (t>>3), bijective over 136 triangular tiles.
// (R3 was an infra failure; identical source resubmitted.)

typedef __attribute__((ext_vector_type(8))) __bf16 bf16x8;
typedef __attribute__((ext_vector_type(4))) float f32x4;

#define BK 64

__device__ __forceinline__ unsigned short f2bf(float f) {
  union { float f; unsigned u; } v; v.f = f;
  unsigned r = v.u + 0x7fffu + ((v.u >> 16) & 1u);  // RNE
  return (unsigned short)(r >> 16);
}

__device__ __forceinline__ void gload_lds16(const void* g, void* l) {
  __builtin_amdgcn_global_load_lds(
      (const __attribute__((address_space(1))) void*)g,
      (__attribute__((address_space(3))) void*)l, 16, 0, 0);
}

// ------------- fused fp32->bf16 conversion (X + weights) + L zero ----------
__global__ __launch_bounds__(256)
void cvt_all(const float* __restrict__ X, const float* __restrict__ Wq,
             const float* __restrict__ Wk, const float* __restrict__ Wv,
             unsigned short* __restrict__ Xbf, unsigned short* __restrict__ Wall,
             float* __restrict__ L) {
  const int bid = blockIdx.x;
  if (bid >= 11264) {  // 4 blocks zero L[4][2048]
    float4* p = (float4*)(L + (size_t)(bid - 11264) * 2048);
    p[threadIdx.x] = (float4){0.f, 0.f, 0.f, 0.f};
    p[threadIdx.x + 256] = (float4){0.f, 0.f, 0.f, 0.f};
    return;
  }
  const float* src;
  unsigned short* dst;
  int i;
  if (bid < 8192) {
    src = X; dst = Xbf; i = bid * 256 + threadIdx.x;
  } else {
    const int m = bid - 8192;
    const int sel = m >> 10;
    src = (sel == 0) ? Wq : (sel == 1) ? Wk : Wv;
    dst = Wall + (size_t)sel * 1048576;
    i = (m & 1023) * 256 + threadIdx.x;
  }
  float4 v = ((const float4*)src)[i];
  ushort4 o;
  o.x = f2bf(v.x); o.y = f2bf(v.y); o.z = f2bf(v.z); o.w = f2bf(v.w);
  ((ushort4*)dst)[i] = o;
}

// -------------------- fused QKV GEMM (128x128, BK=64) --------------------
// A = Xbf [8192][1024], B = Wall [3072][1024]
// grid (24, 64): bx<8 -> Q; bx<16 -> K; else V transposed into Vt[b][e][s].
__global__ __launch_bounds__(256, 3)
void gemm_qkv(const unsigned short* __restrict__ A,
              const unsigned short* __restrict__ Bm,
              unsigned short* __restrict__ Qb,
              unsigned short* __restrict__ Kb,
              unsigned short* __restrict__ Vt)
{
  // T1: bijective XCD swizzle (1536 % 8 == 0). Dispatch order is x-fastest,
  // so lin%8 = XCD id; give each XCD 192 consecutive tiles = 8 full by-rows
  // (A-panel working set 8*256KB = 2MB < 4MB XCD L2).
  const int lin = blockIdx.y * 24 + blockIdx.x;
  const int swz = (lin & 7) * 192 + (lin >> 3);
  const int bx = swz % 24, by = swz / 24;

  __shared__ __align__(16) unsigned short As[128 * BK];  // 16 KB
  __shared__ __align__(16) unsigned short Bs[128 * BK];  // 16 KB

  const int tid = threadIdx.x;
  const int wave = tid >> 6, lane = tid & 63;
  const int wr = wave >> 1, wc = wave & 1;
  const int quad = lane >> 4, l16 = lane & 15;

  const unsigned rsub = wave * 8 + (lane >> 3);
  const unsigned csb = (unsigned)(((lane & 7) ^ ((lane >> 3) & 7)) * 16);  // byte off in row

  // per-lane 32-bit byte offsets; uniform bases stay in SGPRs
  unsigned offA[4], offB[4];
  #pragma unroll
  for (int s = 0; s < 4; ++s) {
    offA[s] = ((unsigned)(by * 128 + s * 32 + rsub) * 1024u) * 2u + csb;
    offB[s] = ((unsigned)(bx * 128 + s * 32 + rsub) * 1024u) * 2u + csb;
  }
  const char* Abase = (const char*)A;
  const char* Bbase = (const char*)Bm;

  f32x4 acc[4][4];
  #pragma unroll
  for (int i = 0; i < 4; ++i)
    #pragma unroll
    for (int j = 0; j < 4; ++j)
      acc[i][j] = (f32x4){0.f, 0.f, 0.f, 0.f};

  const int pq = (quad ^ (l16 & 7)) * 8;
  const int aOff = (wr * 64 + l16) * BK + pq;
  const int bOff = (wc * 64 + l16) * BK + pq;

  for (int k0 = 0; k0 < 1024; k0 += BK) {
    const unsigned kb = (unsigned)k0 * 2u;
    #pragma unroll
    for (int s = 0; s < 4; ++s) {
      gload_lds16(Abase + kb + offA[s], As + s * 2048 + wave * 512);
      gload_lds16(Bbase + kb + offB[s], Bs + s * 2048 + wave * 512);
    }
    __syncthreads();
    #pragma unroll
    for (int h = 0; h < 2; ++h) {
      const int hx = h * 32;
      bf16x8 af[4], bfr[4];
      #pragma unroll
      for (int i = 0; i < 4; ++i)
        af[i] = *(const bf16x8*)(As + ((aOff + i * 16 * BK) ^ hx));
      #pragma unroll
      for (int j = 0; j < 4; ++j)
        bfr[j] = *(const bf16x8*)(Bs + ((bOff + j * 16 * BK) ^ hx));
      #pragma unroll
      for (int i = 0; i < 4; ++i)
        #pragma unroll
        for (int j = 0; j < 4; ++j)
          acc[i][j] = __builtin_amdgcn_mfma_f32_16x16x32_bf16(af[i], bfr[j], acc[i][j], 0, 0, 0);
    }
    __syncthreads();
  }

  const int row0 = by * 128 + wr * 64 + quad * 4;
  const int col0 = bx * 128 + wc * 64 + l16;
  if (bx < 16) {
    unsigned short* C = (bx < 8) ? Qb : Kb;
    const int col = (bx < 8) ? col0 : col0 - 1024;
    #pragma unroll
    for (int i = 0; i < 4; ++i)
      #pragma unroll
      for (int r = 0; r < 4; ++r) {
        const size_t rr = (size_t)(row0 + i * 16 + r) * 1024;
        #pragma unroll
        for (int j = 0; j < 4; ++j)
          C[rr + col + j * 16] = f2bf(acc[i][j][r]);
      }
  } else {
    const int b = row0 >> 11;
    const int s0 = row0 & 2047;
    unsigned short* Vb = Vt + (size_t)b * 2097152;
    #pragma unroll
    for (int j = 0; j < 4; ++j) {
      const size_t ee = (size_t)(col0 - 2048 + j * 16) * 2048;
      #pragma unroll
      for (int i = 0; i < 4; ++i) {
        ushort4 o;
        o.x = f2bf(acc[i][j][0]); o.y = f2bf(acc[i][j][1]);
        o.z = f2bf(acc[i][j][2]); o.w = f2bf(acc[i][j][3]);
        *(ushort4*)(Vb + ee + s0 + i * 16) = o;
      }
    }
  }
}

// -------------------- scores (128x128, BK=64) + exp + rowsum ----------------
// S'[b] = exp(scale*Q@K^T) causal-masked, bf16; L[b][q] += partial rowsums.
// Triangular-packed grid.x (136 tiles), z = batch.
__global__ __launch_bounds__(256, 3)
void gemm_scores(const unsigned short* __restrict__ Q,
                 const unsigned short* __restrict__ Km,
                 unsigned short* __restrict__ S,
                 float* __restrict__ L)
{
  // T1: bijective XCD swizzle over 136 = 8*17 triangular tiles; consecutive
  // t' share by -> Q-panel L2 reuse within an XCD.
  const int t0i = blockIdx.x;
  const int t = (t0i & 7) * 17 + (t0i >> 3);
  const int bz = blockIdx.z;
  int by = (int)((sqrtf(8.f * t + 1.f) - 1.f) * 0.5f);
  while ((by + 1) * (by + 2) / 2 <= t) ++by;
  while (by * (by + 1) / 2 > t) --by;
  const int bx = t - by * (by + 1) / 2;

  __shared__ __align__(16) unsigned short As2[128 * BK];
  __shared__ __align__(16) unsigned short Bs2[128 * BK];

  const int tid = threadIdx.x;
  const int wave = tid >> 6, lane = tid & 63;
  const int wr = wave >> 1, wc = wave & 1;
  const int quad = lane >> 4, l16 = lane & 15;

  const unsigned rsub = wave * 8 + (lane >> 3);
  const unsigned csb = (unsigned)(((lane & 7) ^ ((lane >> 3) & 7)) * 16);

  unsigned offA[4], offB[4];
  #pragma unroll
  for (int s = 0; s < 4; ++s) {
    offA[s] = ((unsigned)(by * 128 + s * 32 + rsub) * 1024u) * 2u + csb;
    offB[s] = ((unsigned)(bx * 128 + s * 32 + rsub) * 1024u) * 2u + csb;
  }
  const char* Abase = (const char*)(Q + (size_t)bz * 2097152);
  const char* Bbase = (const char*)(Km + (size_t)bz * 2097152);

  f32x4 acc[4][4];
  #pragma unroll
  for (int i = 0; i < 4; ++i)
    #pragma unroll
    for (int j = 0; j < 4; ++j)
      acc[i][j] = (f32x4){0.f, 0.f, 0.f, 0.f};

  const int pq = (quad ^ (l16 & 7)) * 8;
  const int aOff = (wr * 64 + l16) * BK + pq;
  const int bOff = (wc * 64 + l16) * BK + pq;

  for (int k0 = 0; k0 < 1024; k0 += BK) {
    const unsigned kb = (unsigned)k0 * 2u;
    #pragma unroll
    for (int s = 0; s < 4; ++s) {
      gload_lds16(Abase + kb + offA[s], As2 + s * 2048 + wave * 512);
      gload_lds16(Bbase + kb + offB[s], Bs2 + s * 2048 + wave * 512);
    }
    __syncthreads();
    #pragma unroll
    for (int h = 0; h < 2; ++h) {
      const int hx = h * 32;
      bf16x8 af[4], bfr[4];
      #pragma unroll
      for (int i = 0; i < 4; ++i)
        af[i] = *(const bf16x8*)(As2 + ((aOff + i * 16 * BK) ^ hx));
      #pragma unroll
      for (int j = 0; j < 4; ++j)
        bfr[j] = *(const bf16x8*)(Bs2 + ((bOff + j * 16 * BK) ^ hx));
      #pragma unroll
      for (int i = 0; i < 4; ++i)
        #pragma unroll
        for (int j = 0; j < 4; ++j)
          acc[i][j] = __builtin_amdgcn_mfma_f32_16x16x32_bf16(af[i], bfr[j], acc[i][j], 0, 0, 0);
    }
    __syncthreads();
  }

  const int row0 = by * 128 + wr * 64 + quad * 4;
  const int col0 = bx * 128 + wc * 64 + l16;
  float* Lb = L + (size_t)bz * 2048;
  unsigned short* C = S + (size_t)bz * 4194304;

  #pragma unroll
  for (int i = 0; i < 4; ++i)
    #pragma unroll
    for (int r = 0; r < 4; ++r) {
      const int grow = row0 + i * 16 + r;
      float ps = 0.f;
      #pragma unroll
      for (int j = 0; j < 4; ++j) {
        const int gcol = col0 + j * 16;
        float e = (gcol <= grow) ? __expf(acc[i][j][r] * 0.03125f) : 0.f;
        acc[i][j][r] = e;
        ps += e;
      }
      #pragma unroll
      for (int m = 8; m > 0; m >>= 1)
        ps += __shfl_xor(ps, m);
      if (l16 == 0) atomicAdd(&Lb[grow], ps);
      const size_t rr = (size_t)grow * 2048;
      #pragma unroll
      for (int j = 0; j < 4; ++j)
        C[rr + col0 + j * 16] = f2bf(acc[i][j][r]);
    }
}

// -------------------- PV (128x128, BK=64) with 1/L normalization ------------
// Out[b] = (P'[b] @ Vt[b]^T) / L; grid (8, 16, 4); kmax = (by+1)*128.
__global__ __launch_bounds__(256, 3)
void gemm_pv(const unsigned short* __restrict__ P,
             const unsigned short* __restrict__ Vt,
             float* __restrict__ Out,
             const float* __restrict__ L)
{
  const int bx = blockIdx.x, by = blockIdx.y, bz = blockIdx.z;

  __shared__ __align__(16) unsigned short As2[128 * BK];
  __shared__ __align__(16) unsigned short Bs2[128 * BK];

  const int tid = threadIdx.x;
  const int wave = tid >> 6, lane = tid & 63;
  const int wr = wave >> 1, wc = wave & 1;
  const int quad = lane >> 4, l16 = lane & 15;

  const unsigned rsub = wave * 8 + (lane >> 3);
  const unsigned csb = (unsigned)(((lane & 7) ^ ((lane >> 3) & 7)) * 16);

  unsigned offA[4], offB[4];
  #pragma unroll
  for (int s = 0; s < 4; ++s) {
    offA[s] = ((unsigned)(by * 128 + s * 32 + rsub) * 2048u) * 2u + csb;
    offB[s] = ((unsigned)(bx * 128 + s * 32 + rsub) * 2048u) * 2u + csb;
  }
  const char* Abase = (const char*)(P + (size_t)bz * 4194304);
  const char* Bbase = (const char*)(Vt + (size_t)bz * 2097152);

  f32x4 acc[4][4];
  #pragma unroll
  for (int i = 0; i < 4; ++i)
    #pragma unroll
    for (int j = 0; j < 4; ++j)
      acc[i][j] = (f32x4){0.f, 0.f, 0.f, 0.f};

  const int kmax = (by + 1) * 128;  // causal truncation, multiple of BK

  const int pq = (quad ^ (l16 & 7)) * 8;
  const int aOff = (wr * 64 + l16) * BK + pq;
  const int bOff = (wc * 64 + l16) * BK + pq;

  for (int k0 = 0; k0 < kmax; k0 += BK) {
    const unsigned kb = (unsigned)k0 * 2u;
    #pragma unroll
    for (int s = 0; s < 4; ++s) {
      gload_lds16(Abase + kb + offA[s], As2 + s * 2048 + wave * 512);
      gload_lds16(Bbase + kb + offB[s], Bs2 + s * 2048 + wave * 512);
    }
    __syncthreads();
    #pragma unroll
    for (int h = 0; h < 2; ++h) {
      const int hx = h * 32;
      bf16x8 af[4], bfr[4];
      #pragma unroll
      for (int i = 0; i < 4; ++i)
        af[i] = *(const bf16x8*)(As2 + ((aOff + i * 16 * BK) ^ hx));
      #pragma unroll
      for (int j = 0; j < 4; ++j)
        bfr[j] = *(const bf16x8*)(Bs2 + ((bOff + j * 16 * BK) ^ hx));
      #pragma unroll
      for (int i = 0; i < 4; ++i)
        #pragma unroll
        for (int j = 0; j < 4; ++j)
          acc[i][j] = __builtin_amdgcn_mfma_f32_16x16x32_bf16(af[i], bfr[j], acc[i][j], 0, 0, 0);
    }
    __syncthreads();
  }

  const int row0 = by * 128 + wr * 64 + quad * 4;
  const int col0 = bx * 128 + wc * 64 + l16;
  float* C = Out + (size_t)bz * 2097152;
  const float* Lb = L + (size_t)bz * 2048;
  #pragma unroll
  for (int i = 0; i < 4; ++i)
    #pragma unroll
    for (int r = 0; r < 4; ++r) {
      const int grow = row0 + i * 16 + r;
      const float inv = 1.0f / Lb[grow];
      const size_t rr = (size_t)grow * 1024;
      #pragma unroll
      for (int j = 0; j < 4; ++j)
        C[rr + col0 + j * 16] = acc[i][j][r] * inv;
    }
}

// -------------------- launch --------------------
extern "C" void kernel_launch(void* const* d_in, const int* in_sizes, int n_in,
                              void* d_out, int out_size, void* d_ws, size_t ws_size,
                              hipStream_t stream) {
  const float* X  = (const float*)d_in[0];
  const float* Wq = (const float*)d_in[1];
  const float* Wk = (const float*)d_in[2];
  const float* Wv = (const float*)d_in[3];
  float* Out = (float*)d_out;

  char* ws = (char*)d_ws;
  unsigned short* Xbf  = (unsigned short*)(ws);              // [8192][1024]    16 MiB
  unsigned short* Wall = (unsigned short*)(ws + 16777216);   // [3072][1024]     6 MiB
  unsigned short* Qbf  = (unsigned short*)(ws + 23068672);   // [8192][1024]    16 MiB
  unsigned short* Kbf  = (unsigned short*)(ws + 39845888);   // [8192][1024]    16 MiB
  unsigned short* Vt   = (unsigned short*)(ws + 56623104);   // [4][1024][2048] 16 MiB
  unsigned short* Sbf  = (unsigned short*)(ws + 73400320);   // [4][2048][2048] 32 MiB
  float*          Lbuf = (float*)(ws + 106954752);           // [4][2048]       32 KiB

  cvt_all<<<11268, 256, 0, stream>>>(X, Wq, Wk, Wv, Xbf, Wall, Lbuf);

  gemm_qkv<<<dim3(24, 64), 256, 0, stream>>>(Xbf, Wall, Qbf, Kbf, Vt);

  gemm_scores<<<dim3(136, 1, 4), 256, 0, stream>>>(Qbf, Kbf, Sbf, Lbuf);

  gemm_pv<<<dim3(8, 16, 4), 256, 0, stream>>>(Sbf, Vt, Out, Lbuf);
}